// Round 2
// baseline (265.320 us; speedup 1.0000x reference)
//
#include <hip/hip_runtime.h>
#include <hip/hip_bf16.h>
#include <hip/hip_fp16.h>
#include <math.h>

// Problem constants (B,S,H,M) = (8,128,768,128)
#define B_   8
#define S_   128
#define H_   768
#define M_   128
#define P_   8256      // S*(S+1)/2 pairs per batch
#define BP_  66048     // B_ * P_
#define EPSF 1e-12f

typedef unsigned short u16;
typedef unsigned int   u32;
typedef _Float16 h16;
typedef _Float16 ffrag __attribute__((ext_vector_type(8)));   // 8 f16 = 4 VGPR
typedef float    f32x4 __attribute__((ext_vector_type(4)));

// packed f16 fma on two lanes packed in a u32: one v_pk_fma_f16
__device__ __forceinline__ u32 fuse2(u32 x, u32 g, u32 b) {
    __half2 r = __hfma2(__builtin_bit_cast(__half2, x),
                        __builtin_bit_cast(__half2, g),
                        __builtin_bit_cast(__half2, b));
    return __builtin_bit_cast(u32, r);
}
__device__ __forceinline__ float fast_tanh(float v) {
    float e = __expf(-2.0f * fabsf(v));
    float t = (1.0f - e) / (1.0f + e);
    return copysignf(t, v);
}

// ============ kernel 0: convert weights to f16; build WcT[n][h]; biasc ============
__global__ void k_convert(const float* __restrict__ wg, const float* __restrict__ wb,
                          const float* __restrict__ we, const float* __restrict__ wh,
                          const float* __restrict__ wt,
                          const float* __restrict__ be, const float* __restrict__ bh,
                          const float* __restrict__ bt,
                          h16* __restrict__ wgb, h16* __restrict__ wbb,
                          h16* __restrict__ wct, float* __restrict__ biasc)
{
    int idx = blockIdx.x * 256 + threadIdx.x;
    if (idx < 589824) {
        wgb[idx] = (h16)wg[idx];
    } else if (idx < 1179648) {
        int i = idx - 589824;
        wbb[i] = (h16)wb[i];
    } else if (idx < 1474560) {
        int i = idx - 1179648;              // [0, 294912) : n in [0,384), h in [0,768)
        int n = i / 768, h = i - n * 768;
        const float* w = (n < 128) ? we : (n < 256 ? wh : wt);
        wct[i] = (h16)w[h * 128 + (n & 127)];
    } else if (idx < 1474944) {
        int n = idx - 1474560;              // [0,384)
        biasc[n] = (n < 128) ? be[n] : (n < 256 ? bh[n - 128] : bt[n - 256]);
    }
}

// ============ kernel 1: per-row normalize + seq->f16 ============
// xn[row] = (x - mean) / (var + eps)^2   (reference squares, no sqrt!)
__global__ void k_norm(const float* __restrict__ seq, h16* __restrict__ xn, h16* __restrict__ condb)
{
    __shared__ float red[4];
    const int row = blockIdx.x;
    const int t = threadIdx.x;
    const int lane = t & 63, wid = t >> 6;
    const float* x = seq + (size_t)row * H_;
    float x0 = x[t], x1 = x[t + 256], x2 = x[t + 512];

    float s = x0 + x1 + x2;
    for (int o = 32; o; o >>= 1) s += __shfl_xor(s, o);
    if (lane == 0) red[wid] = s;
    __syncthreads();
    float mean = (red[0] + red[1] + red[2] + red[3]) * (1.0f / 768.0f);

    float c0 = x0 - mean, c1 = x1 - mean, c2 = x2 - mean;
    float ss = c0 * c0 + c1 * c1 + c2 * c2;
    for (int o = 32; o; o >>= 1) ss += __shfl_xor(ss, o);
    __syncthreads();
    if (lane == 0) red[wid] = ss;
    __syncthreads();
    float var = (red[0] + red[1] + red[2] + red[3]) * (1.0f / 768.0f);
    float sd = var + EPSF;
    float scale = 1.0f / (sd * sd);

    h16* xr = xn + (size_t)row * H_;
    h16* cr = condb + (size_t)row * H_;
    xr[t] = (h16)(c0 * scale); xr[t + 256] = (h16)(c1 * scale); xr[t + 512] = (h16)(c2 * scale);
    cr[t] = (h16)x0;           cr[t + 256] = (h16)x1;           cr[t + 512] = (h16)x2;
}

// ============ kernel 2: cond GEMM -> gamma_c / beta_c (f16) ============
// C[p][o] = sum_h cond[p][h] * W[o][h] + bias[o];  tiles 64x64, BK=64
// grid (16, 24): by<12 -> gamma cols by*64 ; else beta cols (by-12)*64
__global__ __launch_bounds__(256) void k_cond_gemm(
    const h16* __restrict__ Ab, const h16* __restrict__ Wg, const h16* __restrict__ Wb,
    const float* __restrict__ gamma, const float* __restrict__ beta,
    h16* __restrict__ Gc, h16* __restrict__ Bc)
{
    __shared__ h16 Ash[64 * 72];
    __shared__ h16 Bsh[64 * 72];
    const int t = threadIdx.x;
    const int row0 = blockIdx.x * 64;
    const int by = blockIdx.y;
    const bool isg = (by < 12);
    const int nc0 = (isg ? by : by - 12) * 64;
    const h16* wsrc = isg ? Wg : Wb;

    const int r = t >> 2, q = t & 3;               // r in [0,64), 16 elems each at q*16
    const h16* ap = Ab + (size_t)(row0 + r) * H_ + q * 16;
    const h16* wp = wsrc + (size_t)(nc0 + r) * H_ + q * 16;
    h16* asto = &Ash[r * 72 + q * 16];
    h16* bsto = &Bsh[r * 72 + q * 16];

    const int lane = t & 63, wid = t >> 6;
    const int wm0 = (wid >> 1) * 32, wn0 = (wid & 1) * 32;
    const int l15 = lane & 15, quad = lane >> 4, q8 = quad * 8;

    f32x4 acc[2][2] = {};
    for (int kt = 0; kt < 12; ++kt) {
        const int k0 = kt * 64;
        uint4 a0 = *(const uint4*)(ap + k0); uint4 a1 = *(const uint4*)(ap + k0 + 8);
        uint4 w0 = *(const uint4*)(wp + k0); uint4 w1 = *(const uint4*)(wp + k0 + 8);
        *(uint4*)asto = a0; *(uint4*)(asto + 8) = a1;
        *(uint4*)bsto = w0; *(uint4*)(bsto + 8) = w1;
        __syncthreads();
#pragma unroll
        for (int ks = 0; ks < 64; ks += 32) {
            ffrag af[2], bf[2];
#pragma unroll
            for (int mi = 0; mi < 2; ++mi)
                af[mi] = *reinterpret_cast<const ffrag*>(&Ash[(wm0 + mi * 16 + l15) * 72 + ks + q8]);
#pragma unroll
            for (int ni = 0; ni < 2; ++ni)
                bf[ni] = *reinterpret_cast<const ffrag*>(&Bsh[(wn0 + ni * 16 + l15) * 72 + ks + q8]);
#pragma unroll
            for (int mi = 0; mi < 2; ++mi)
#pragma unroll
                for (int ni = 0; ni < 2; ++ni)
                    acc[mi][ni] = __builtin_amdgcn_mfma_f32_16x16x32_f16(af[mi], bf[ni], acc[mi][ni], 0, 0, 0);
        }
        __syncthreads();
    }

    const float* bias = isg ? gamma : beta;
    h16* outp = isg ? Gc : Bc;
#pragma unroll
    for (int mi = 0; mi < 2; ++mi)
#pragma unroll
        for (int ni = 0; ni < 2; ++ni) {
            int c = wn0 + ni * 16 + l15;
            float bv = bias[nc0 + c];
#pragma unroll
            for (int reg = 0; reg < 4; ++reg) {
                int rg = wm0 + mi * 16 + quad * 4 + reg;   // C/D: col=lane&15, row=quad*4+reg (m89)
                outp[(size_t)(row0 + rg) * H_ + nc0 + c] = (h16)(acc[mi][ni][reg] + bv);
            }
        }
}

// ============ kernel 3: fused pair GEMM, all 3 heads ============
// rows = global pair index gp in [0,66048); cols = 192-wide half of the 384
// combined [ent|head|tail] output space.  BK=64, 12 iters.
// A[gp][h] = xn[b,j,h]*Gc[b,i,h] + Bc[b,i,h]  (f16, one v_pk_fma_f16 per 2 elems)
__global__ __launch_bounds__(256) void k_pair_gemm(
    const h16* __restrict__ Xn, const h16* __restrict__ Gcb, const h16* __restrict__ Bcb,
    const h16* __restrict__ WcT, const float* __restrict__ biasc,
    float* __restrict__ out)
{
    __shared__ h16 Ash[128 * 72];   // 18.4 KB
    __shared__ h16 Bsh[192 * 72];   // 27.6 KB
    __shared__ int offx[128];       // xn row index (b*128 + j)
    __shared__ int offc[128];       // cond row index (b*128 + i)

    const int t = threadIdx.x;
    const int row0 = blockIdx.x * 128;
    const int nb = blockIdx.y;              // 0/1 -> cols [0,192) / [192,384)

    if (t < 128) {
        int gp = row0 + t;
        int b = gp / P_;
        int p = gp - b * P_;
        int i = (int)((257.0f - sqrtf(66049.0f - 8.0f * (float)p)) * 0.5f);
        if (i < 0) i = 0; if (i > 127) i = 127;
        while (i > 0 && (i * (257 - i)) / 2 > p) --i;
        while (((i + 1) * (256 - i)) / 2 <= p) ++i;
        int j = i + (p - (i * (257 - i)) / 2);
        offx[t] = b * 128 + j;
        offc[t] = b * 128 + i;
    }
    __syncthreads();

    // A staging: thread covers 32 elems of row r=t>>1 at k-offset (t&1)*32
    const int r = t >> 1, half = t & 1;
    const h16* xp  = Xn  + (size_t)offx[r] * H_ + half * 32;
    const h16* gp_ = Gcb + (size_t)offc[r] * H_ + half * 32;
    const h16* bp_ = Bcb + (size_t)offc[r] * H_ + half * 32;
    h16* asto = &Ash[r * 72 + half * 32];
    // B staging: 6 chunks/thread, chunk g = t + 256*i: row=g>>3, kc=g&7
    const h16* wbase = WcT + (size_t)nb * 192 * H_;

    const int lane = t & 63, wid = t >> 6;
    const int wm0 = (wid >> 1) * 64, wn0 = (wid & 1) * 96;
    const int l15 = lane & 15, quad = lane >> 4, q8 = quad * 8;

    f32x4 acc[4][6] = {};
    for (int kt = 0; kt < 12; ++kt) {
        const int k0 = kt * 64;
        // ---- A: load 3 sources (4 uint4 each), fuse, store 4x b128 ----
        uint4 xv0 = *(const uint4*)(xp + k0);       uint4 xv1 = *(const uint4*)(xp + k0 + 8);
        uint4 xv2 = *(const uint4*)(xp + k0 + 16);  uint4 xv3 = *(const uint4*)(xp + k0 + 24);
        uint4 gv0 = *(const uint4*)(gp_ + k0);      uint4 gv1 = *(const uint4*)(gp_ + k0 + 8);
        uint4 gv2 = *(const uint4*)(gp_ + k0 + 16); uint4 gv3 = *(const uint4*)(gp_ + k0 + 24);
        uint4 bv0 = *(const uint4*)(bp_ + k0);      uint4 bv1 = *(const uint4*)(bp_ + k0 + 8);
        uint4 bv2 = *(const uint4*)(bp_ + k0 + 16); uint4 bv3 = *(const uint4*)(bp_ + k0 + 24);
        // ---- B: 6 chunks ----
        uint4 wv[6];
#pragma unroll
        for (int i6 = 0; i6 < 6; ++i6) {
            int g = t + 256 * i6;
            int brow = g >> 3, kc = g & 7;
            wv[i6] = *(const uint4*)(wbase + (size_t)brow * H_ + k0 + kc * 8);
        }
        uint4 a0, a1, a2, a3;
        a0.x = fuse2(xv0.x, gv0.x, bv0.x); a0.y = fuse2(xv0.y, gv0.y, bv0.y);
        a0.z = fuse2(xv0.z, gv0.z, bv0.z); a0.w = fuse2(xv0.w, gv0.w, bv0.w);
        a1.x = fuse2(xv1.x, gv1.x, bv1.x); a1.y = fuse2(xv1.y, gv1.y, bv1.y);
        a1.z = fuse2(xv1.z, gv1.z, bv1.z); a1.w = fuse2(xv1.w, gv1.w, bv1.w);
        a2.x = fuse2(xv2.x, gv2.x, bv2.x); a2.y = fuse2(xv2.y, gv2.y, bv2.y);
        a2.z = fuse2(xv2.z, gv2.z, bv2.z); a2.w = fuse2(xv2.w, gv2.w, bv2.w);
        a3.x = fuse2(xv3.x, gv3.x, bv3.x); a3.y = fuse2(xv3.y, gv3.y, bv3.y);
        a3.z = fuse2(xv3.z, gv3.z, bv3.z); a3.w = fuse2(xv3.w, gv3.w, bv3.w);
        *(uint4*)asto = a0; *(uint4*)(asto + 8) = a1;
        *(uint4*)(asto + 16) = a2; *(uint4*)(asto + 24) = a3;
#pragma unroll
        for (int i6 = 0; i6 < 6; ++i6) {
            int g = t + 256 * i6;
            int brow = g >> 3, kc = g & 7;
            *(uint4*)&Bsh[brow * 72 + kc * 8] = wv[i6];
        }
        __syncthreads();
#pragma unroll
        for (int ks = 0; ks < 64; ks += 32) {
            ffrag af[4], bf[6];
#pragma unroll
            for (int mi = 0; mi < 4; ++mi)
                af[mi] = *reinterpret_cast<const ffrag*>(&Ash[(wm0 + mi * 16 + l15) * 72 + ks + q8]);
#pragma unroll
            for (int ni = 0; ni < 6; ++ni)
                bf[ni] = *reinterpret_cast<const ffrag*>(&Bsh[(wn0 + ni * 16 + l15) * 72 + ks + q8]);
#pragma unroll
            for (int mi = 0; mi < 4; ++mi)
#pragma unroll
                for (int ni = 0; ni < 6; ++ni)
                    acc[mi][ni] = __builtin_amdgcn_mfma_f32_16x16x32_f16(af[mi], bf[ni], acc[mi][ni], 0, 0, 0);
        }
        __syncthreads();
    }

#pragma unroll
    for (int mi = 0; mi < 4; ++mi)
#pragma unroll
        for (int ni = 0; ni < 6; ++ni) {
            int cg = nb * 192 + wn0 + ni * 16 + l15;   // global col in [0,384)
            int head = cg >> 7, m = cg & 127;
            float bv = biasc[cg];
#pragma unroll
            for (int reg = 0; reg < 4; ++reg) {
                int rg = wm0 + mi * 16 + quad * 4 + reg;
                size_t gp2 = (size_t)row0 + rg;
                out[((size_t)head * BP_ + gp2) * M_ + m] = fast_tanh(acc[mi][ni][reg] + bv);
            }
        }
}

extern "C" void kernel_launch(void* const* d_in, const int* in_sizes, int n_in,
                              void* d_out, int out_size, void* d_ws, size_t ws_size,
                              hipStream_t stream)
{
    const float* seq     = (const float*)d_in[0];
    const float* gamma   = (const float*)d_in[1];
    const float* beta    = (const float*)d_in[2];
    const float* w_beta  = (const float*)d_in[3];
    const float* w_gamma = (const float*)d_in[4];
    const float* w_ent   = (const float*)d_in[5];
    const float* b_ent   = (const float*)d_in[6];
    const float* w_head  = (const float*)d_in[7];
    const float* b_head  = (const float*)d_in[8];
    const float* w_tail  = (const float*)d_in[9];
    const float* b_tail  = (const float*)d_in[10];
    float* out = (float*)d_out;

    // workspace layout (all 16B-aligned)
    char* ws = (char*)d_ws;
    h16* xn    = (h16*)ws; ws += (size_t)1024 * 768 * 2;  // normalized rows, f16
    h16* condb = (h16*)ws; ws += (size_t)1024 * 768 * 2;  // seq as f16
    h16* wgb   = (h16*)ws; ws += (size_t)768 * 768 * 2;   // w_gamma f16 [o][h]
    h16* wbb   = (h16*)ws; ws += (size_t)768 * 768 * 2;   // w_beta  f16 [o][h]
    h16* wct   = (h16*)ws; ws += (size_t)384 * 768 * 2;   // [n][h] combined ent|head|tail
    h16* gc    = (h16*)ws; ws += (size_t)1024 * 768 * 2;  // gamma_c f16
    h16* bc    = (h16*)ws; ws += (size_t)1024 * 768 * 2;  // beta_c  f16
    float* biasc = (float*)ws; ws += 384 * 4;             // [ent|head|tail] bias

    hipLaunchKernelGGL(k_convert, dim3(5763), dim3(256), 0, stream,
                       w_gamma, w_beta, w_ent, w_head, w_tail, b_ent, b_head, b_tail,
                       wgb, wbb, wct, biasc);
    hipLaunchKernelGGL(k_norm, dim3(1024), dim3(256), 0, stream, seq, xn, condb);
    hipLaunchKernelGGL(k_cond_gemm, dim3(16, 24), dim3(256), 0, stream,
                       condb, wgb, wbb, gamma, beta, gc, bc);
    hipLaunchKernelGGL(k_pair_gemm, dim3(516, 2), dim3(256), 0, stream,
                       xn, gc, bc, wct, biasc, out);
}